// Round 2
// baseline (1405.628 us; speedup 1.0000x reference)
//
#include <hip/hip_runtime.h>
#include <math.h>

#define NROWS 16384
#define KC 8192
#define DD 256
#define RB 64          // rows per block (kernel1)
#define CB 128         // codes per K-tile
#define DK 64          // d-chunk
#define NKT (KC / CB)  // 64
#define NDC (DD / DK)  // 4
#define CS_STRIDE 132  // padded LDS stride for code tile

// ---------------------------------------------------------------------------
// numpy pairwise sum of squares over 256 contiguous floats, bit-faithful to
// np.sum(x*x, axis=-1): two 128-wide base cases (8 accumulators, tree
// combine), then S0+S1. Products rounded separately (no FMA contraction).
// ---------------------------------------------------------------------------
__device__ __forceinline__ float np_sumsq_256(const float* __restrict__ p)
{
    float S[2];
#pragma unroll
    for (int h = 0; h < 2; ++h) {
        const float* q = p + 128 * h;
        float r[8];
        float4 v0 = *(const float4*)(q);
        float4 v1 = *(const float4*)(q + 4);
        r[0] = __fmul_rn(v0.x, v0.x); r[1] = __fmul_rn(v0.y, v0.y);
        r[2] = __fmul_rn(v0.z, v0.z); r[3] = __fmul_rn(v0.w, v0.w);
        r[4] = __fmul_rn(v1.x, v1.x); r[5] = __fmul_rn(v1.y, v1.y);
        r[6] = __fmul_rn(v1.z, v1.z); r[7] = __fmul_rn(v1.w, v1.w);
#pragma unroll
        for (int i = 8; i < 128; i += 8) {
            float4 w0 = *(const float4*)(q + i);
            float4 w1 = *(const float4*)(q + i + 4);
            r[0] = __fadd_rn(r[0], __fmul_rn(w0.x, w0.x));
            r[1] = __fadd_rn(r[1], __fmul_rn(w0.y, w0.y));
            r[2] = __fadd_rn(r[2], __fmul_rn(w0.z, w0.z));
            r[3] = __fadd_rn(r[3], __fmul_rn(w0.w, w0.w));
            r[4] = __fadd_rn(r[4], __fmul_rn(w1.x, w1.x));
            r[5] = __fadd_rn(r[5], __fmul_rn(w1.y, w1.y));
            r[6] = __fadd_rn(r[6], __fmul_rn(w1.z, w1.z));
            r[7] = __fadd_rn(r[7], __fmul_rn(w1.w, w1.w));
        }
        S[h] = __fadd_rn(__fadd_rn(__fadd_rn(r[0], r[1]), __fadd_rn(r[2], r[3])),
                         __fadd_rn(__fadd_rn(r[4], r[5]), __fadd_rn(r[6], r[7])));
    }
    return __fadd_rn(S[0], S[1]);
}

// ---------------------------------------------------------------------------
// Kernel 0: cc[k] = np_sumsq(codebook[k]); rowA[n] = np_sumsq(z[n]); zero loss.
// One thread per unit (8192 codes + 16384 rows).
// ---------------------------------------------------------------------------
__global__ __launch_bounds__(256)
void vq_norms_kernel(const float* __restrict__ z, const float* __restrict__ cb,
                     float* __restrict__ cc, float* __restrict__ rowA,
                     float* __restrict__ loss_ptr)
{
    const int u = blockIdx.x * 256 + threadIdx.x;   // 0 .. 24575
    if (u < KC) {
        cc[u] = np_sumsq_256(cb + (size_t)u * DD);
    } else {
        rowA[u - KC] = np_sumsq_256(z + (size_t)(u - KC) * DD);
    }
    if (u == 0) *loss_ptr = 0.0f;
}

// ---------------------------------------------------------------------------
// Kernel 1: per row argmin_k of d2 = fl(fl(A_n - 2*(z.c)) + C_k), replicating
// the np fp32 rounding. fp32 register-tiled GEMM; 256 threads, 64 rows/block,
// K-tiles of 128 codes, d-chunks of 64. Lowest-index tie-break throughout.
// ---------------------------------------------------------------------------
__global__ __launch_bounds__(256, 1)
void vq_argmin_kernel(const float* __restrict__ z, const float* __restrict__ cb,
                      const float* __restrict__ cc, const float* __restrict__ rowA,
                      int* __restrict__ out_idx)
{
    __shared__ float zs[DD * RB];          // [d][r], 64 KB
    __shared__ float cs[DK * CS_STRIDE];   // [d][c swizzled], 33 KB

    const int t = threadIdx.x;
    const int tx = t & 15;   // code group (16)
    const int ty = t >> 4;   // row group (16)
    const int rowbase = blockIdx.x * RB;

    // per-thread row norms A (4 rows)
    float Av[4];
#pragma unroll
    for (int i = 0; i < 4; ++i) Av[i] = rowA[rowbase + 4 * ty + i];

    // ---- load z tile transposed into LDS: zs[d][r]
    {
        const int r = t >> 2;
        const int dbase = (t & 3) * 64;
        const float* src = z + (size_t)(rowbase + r) * DD + dbase;
#pragma unroll
        for (int i = 0; i < 16; ++i) {
            float4 v = *(const float4*)(src + 4 * i);
            const int d = dbase + 4 * i;
            zs[(d + 0) * RB + r] = v.x;
            zs[(d + 1) * RB + r] = v.y;
            zs[(d + 2) * RB + r] = v.z;
            zs[(d + 3) * RB + r] = v.w;
        }
    }

    float bestv[4];
    int besti[4];
#pragma unroll
    for (int i = 0; i < 4; ++i) { bestv[i] = 3.0e38f; besti[i] = 0; }

    // codebook chunk prefetch registers.
    const int lu = t & 15;
    const int lv = t >> 4;
    float4 pre[8];
    {
        const float* base = cb + (size_t)lv * DD + 4 * lu;   // kt=0, dc=0
#pragma unroll
        for (int i = 0; i < 8; ++i)
            pre[i] = *(const float4*)(base + (size_t)(16 * i) * DD);
    }

    for (int kt = 0; kt < NKT; ++kt) {
        float ccv[8];
        {
            const float* cbase = cc + kt * CB;
#pragma unroll
            for (int j = 0; j < 4; ++j) ccv[j] = cbase[4 * tx + j];
#pragma unroll
            for (int j = 0; j < 4; ++j) ccv[4 + j] = cbase[64 + 4 * tx + j];
        }

        float acc[4][8];
#pragma unroll
        for (int i = 0; i < 4; ++i)
#pragma unroll
            for (int j = 0; j < 8; ++j) acc[i][j] = 0.0f;

        for (int dc = 0; dc < NDC; ++dc) {
            __syncthreads();   // previous chunk's consumers done (also covers zs)
            // store pre -> cs (transposed, chunk-XOR swizzle on code bits 2-3)
            {
                const int colx = lv ^ ((lu & 3) << 2);
                const int dbase = 4 * lu;
#pragma unroll
                for (int i = 0; i < 8; ++i) {
                    const int col = 16 * i + colx;
                    cs[(dbase + 0) * CS_STRIDE + col] = pre[i].x;
                    cs[(dbase + 1) * CS_STRIDE + col] = pre[i].y;
                    cs[(dbase + 2) * CS_STRIDE + col] = pre[i].z;
                    cs[(dbase + 3) * CS_STRIDE + col] = pre[i].w;
                }
            }
            // issue next chunk's global loads (overlap with compute below)
            {
                int ndc = dc + 1, nkt = kt;
                if (ndc == NDC) { ndc = 0; ++nkt; }
                if (nkt < NKT) {
                    const float* base =
                        cb + (size_t)(nkt * CB + lv) * DD + ndc * DK + 4 * lu;
#pragma unroll
                    for (int i = 0; i < 8; ++i)
                        pre[i] = *(const float4*)(base + (size_t)(16 * i) * DD);
                }
            }
            __syncthreads();   // cs ready
            // compute: 64 d-steps, sequential d order => single fma chain per
            // (row, code), matching BLAS sgemm's k-ascending fma accumulation.
            const float* zchunk = zs + (size_t)(dc * DK) * RB + 4 * ty;
#pragma unroll 4
            for (int dd = 0; dd < 16; ++dd) {
                const int sw = (dd & 3) << 2;
                const int c0 = (4 * tx) ^ sw;
#pragma unroll
                for (int l = 0; l < 4; ++l) {
                    const int d = 4 * dd + l;
                    float4 a = *(const float4*)(zchunk + (size_t)d * RB);
                    const float* crow = cs + (size_t)d * CS_STRIDE;
                    float4 b0 = *(const float4*)(crow + c0);
                    float4 b1 = *(const float4*)(crow + c0 + 64);
                    float av[4] = {a.x, a.y, a.z, a.w};
                    float bv[8] = {b0.x, b0.y, b0.z, b0.w,
                                   b1.x, b1.y, b1.z, b1.w};
#pragma unroll
                    for (int i = 0; i < 4; ++i)
#pragma unroll
                        for (int j = 0; j < 8; ++j)
                            acc[i][j] = fmaf(av[i], bv[j], acc[i][j]);
                }
            }
        }

        // finalize tile: d2 = fl(fl(A - 2*dot) + C); strict < keeps lowest idx
#pragma unroll
        for (int j = 0; j < 8; ++j) {
            const int code = kt * CB + ((j < 4) ? (4 * tx + j)
                                               : (64 + 4 * tx + (j - 4)));
#pragma unroll
            for (int i = 0; i < 4; ++i) {
                const float tzb = __fsub_rn(Av[i], 2.0f * acc[i][j]); // 2*acc exact
                const float d2 = __fadd_rn(tzb, ccv[j]);
                if (d2 < bestv[i]) { bestv[i] = d2; besti[i] = code; }
            }
        }
    }

    // cross-thread per-row reduction (16 candidates per row), lexicographic
    __syncthreads();
    float* rv = cs;                  // [64][16]
    int* ri = (int*)(cs + 1024);     // [64][16]
#pragma unroll
    for (int i = 0; i < 4; ++i) {
        rv[(4 * ty + i) * 16 + tx] = bestv[i];
        ri[(4 * ty + i) * 16 + tx] = besti[i];
    }
    __syncthreads();
    if (t < 64) {
        float v = rv[t * 16];
        int idx = ri[t * 16];
#pragma unroll
        for (int x = 1; x < 16; ++x) {
            const float vx = rv[t * 16 + x];
            const int ix = ri[t * 16 + x];
            if (vx < v || (vx == v && ix < idx)) { v = vx; idx = ix; }
        }
        out_idx[rowbase + t] = idx;
    }
}

// ---------------------------------------------------------------------------
// Kernel 2: gather c*, z_q, loss, indices-as-float. One wave per row.
// ---------------------------------------------------------------------------
__global__ __launch_bounds__(256)
void vq_out_kernel(const float* __restrict__ z, const float* __restrict__ cb,
                   const int* __restrict__ idx, float* __restrict__ zq,
                   float* __restrict__ loss_ptr, float* __restrict__ idx_out)
{
    __shared__ float wsum[4];
    const int t = threadIdx.x;
    const int lane = t & 63;
    const int wv = t >> 6;
    const int row = blockIdx.x * 4 + wv;
    const int k = idx[row];
    const float4 z4 = *(const float4*)(z + (size_t)row * DD + lane * 4);
    const float4 c4 = *(const float4*)(cb + (size_t)k * DD + lane * 4);
    float4 d4 = make_float4(c4.x - z4.x, c4.y - z4.y, c4.z - z4.z, c4.w - z4.w);
    float ss = fmaf(d4.x, d4.x, fmaf(d4.y, d4.y, fmaf(d4.z, d4.z, d4.w * d4.w)));
#pragma unroll
    for (int m = 1; m < 64; m <<= 1) ss += __shfl_xor(ss, m, 64);
    const float mag = sqrtf(ss);
    const float scale = mag / (mag + 1e-8f);
    float4 q = make_float4(fmaf(scale, d4.x, z4.x), fmaf(scale, d4.y, z4.y),
                           fmaf(scale, d4.z, z4.z), fmaf(scale, d4.w, z4.w));
    *(float4*)(zq + (size_t)row * DD + lane * 4) = q;
    if (lane == 0) {
        wsum[wv] = ss;
        idx_out[row] = (float)k;
    }
    __syncthreads();
    if (t == 0) {
        const float s = (wsum[0] + wsum[1]) + (wsum[2] + wsum[3]);
        atomicAdd(loss_ptr, s * (1.25f / 4194304.0f));
    }
}

// ---------------------------------------------------------------------------
extern "C" void kernel_launch(void* const* d_in, const int* in_sizes, int n_in,
                              void* d_out, int out_size, void* d_ws, size_t ws_size,
                              hipStream_t stream)
{
    (void)in_sizes; (void)n_in; (void)out_size; (void)ws_size;
    const float* z = (const float*)d_in[0];
    const float* cb = (const float*)d_in[1];
    float* out = (float*)d_out;
    float* zq = out;                                 // [0, 4194304)
    float* loss_ptr = out + (size_t)NROWS * DD;      // [4194304]
    float* idx_out = loss_ptr + 1;                   // [4194305, +16384)

    int* idx_ws = (int*)d_ws;                                      // 16384 ints
    float* cc = (float*)((char*)d_ws + 64 * 1024);                 // 8192 floats
    float* rowA = (float*)((char*)d_ws + 96 * 1024);               // 16384 floats

    vq_norms_kernel<<<(KC + NROWS) / 256, 256, 0, stream>>>(z, cb, cc, rowA, loss_ptr);
    vq_argmin_kernel<<<NROWS / RB, 256, 0, stream>>>(z, cb, cc, rowA, idx_ws);
    vq_out_kernel<<<NROWS / 4, 256, 0, stream>>>(z, cb, idx_ws, zq, loss_ptr, idx_out);
}

// Round 3
// 713.218 us; speedup vs baseline: 1.9708x; 1.9708x over previous
//
#include <hip/hip_runtime.h>
#include <math.h>

#define NROWS 16384
#define KC 8192
#define DD 256
#define CAP 128
#define MARGIN 1.5e-3f

typedef __attribute__((ext_vector_type(8))) short bf16x8;
typedef __attribute__((ext_vector_type(4))) float f32x4;

__device__ __forceinline__ unsigned short f2bf(float f) {
    unsigned int u = __float_as_uint(f);
    unsigned int r = (u + 0x7FFFu + ((u >> 16) & 1u)) >> 16;   // RNE
    return (unsigned short)r;
}
__device__ __forceinline__ unsigned int fenc(float f) {        // monotone f32->u32
    unsigned int u = __float_as_uint(f);
    return (u & 0x80000000u) ? ~u : (u | 0x80000000u);
}
__device__ __forceinline__ float fdec(unsigned int u) {
    return __uint_as_float((u & 0x80000000u) ? (u & 0x7FFFFFFFu) : ~u);
}

// ---------------------------------------------------------------------------
// Convert z and codebook to bf16 (RNE). One float4 per thread.
// ---------------------------------------------------------------------------
__global__ __launch_bounds__(256)
void vq_convert(const float* __restrict__ z, const float* __restrict__ cb,
                unsigned short* __restrict__ zb, unsigned short* __restrict__ cbb)
{
    const size_t i = (size_t)blockIdx.x * 256 + threadIdx.x;   // float4 index
    const float* src; unsigned short* dst; size_t off;
    if (i < 1048576) { src = z;  dst = zb;  off = i; }
    else             { src = cb; dst = cbb; off = i - 1048576; }
    float4 v = *(const float4*)(src + off * 4);
    ushort4 o;
    o.x = f2bf(v.x); o.y = f2bf(v.y); o.z = f2bf(v.z); o.w = f2bf(v.w);
    *(ushort4*)(dst + off * 4) = o;
}

// ---------------------------------------------------------------------------
// np-pairwise sum-of-squares norms, 16 lanes per unit (bit-faithful to
// np.sum(x*x,-1): 8 accumulators per 128-half, commutative tree combine).
// units: [0,KC) -> cc, [KC, KC+NROWS) -> rowA. Also zero loss.
// ---------------------------------------------------------------------------
__global__ __launch_bounds__(256)
void vq_norms(const float* __restrict__ z, const float* __restrict__ cb,
              float* __restrict__ cc, float* __restrict__ rowA,
              float* __restrict__ loss_ptr)
{
    const int t = threadIdx.x;
    const int unit = blockIdx.x * 16 + (t >> 4);
    const int l = t & 15;
    const float* p = (unit < KC) ? (cb + (size_t)unit * DD)
                                 : (z + (size_t)(unit - KC) * DD);
    const float* q = p + 128 * (l >> 3) + (l & 7);
    float x0 = q[0];
    float r = __fmul_rn(x0, x0);
#pragma unroll
    for (int i = 1; i < 16; ++i) {
        const float x = q[8 * i];
        r = __fadd_rn(r, __fmul_rn(x, x));
    }
    r = __fadd_rn(r, __shfl_xor(r, 1, 64));
    r = __fadd_rn(r, __shfl_xor(r, 2, 64));
    r = __fadd_rn(r, __shfl_xor(r, 4, 64));
    r = __fadd_rn(r, __shfl_xor(r, 8, 64));
    if (l == 0) {
        if (unit < KC) cc[unit] = r;
        else rowA[unit - KC] = r;
        if (unit == 0) *loss_ptr = 0.0f;
    }
}

// ---------------------------------------------------------------------------
// MFMA screen: disc[k][n] = cc[k] - 2 * (cb_bf16[k] . z_bf16[n]) over a
// 128-code x 128-row tile, K=256 fully LDS-resident, XOR-swizzled.
// Per z-row: tile col-min -> global atomicMin rowmin; record candidate codes
// with disc <= rowmin + MARGIN.
// ---------------------------------------------------------------------------
__global__ __launch_bounds__(256, 1)
void vq_gemm_screen(const unsigned short* __restrict__ cbb,
                    const unsigned short* __restrict__ zb,
                    const float* __restrict__ cc,
                    unsigned int* __restrict__ rowmin_u,
                    int* __restrict__ cnt, int* __restrict__ cand)
{
    __shared__ char Als[65536];           // codes [128][256 bf16], swizzled
    __shared__ char Bls[65536];           // rows  [128][256 bf16], swizzled
    __shared__ float ccs[128];
    __shared__ float colmin_lds[2][128];
    __shared__ float thr_lds[128];

    const int t = threadIdx.x;
    const int lane = t & 63;
    const int w = t >> 6;       // wave 0..3
    const int cw = w >> 1;      // code half
    const int rw = w & 1;       // row half
    const int gx = blockIdx.x;  // code tile (64)
    const int gy = blockIdx.y;  // row tile (128)

    // ---- stage tiles (coalesced global, swizzled ds_write_b128)
    {
        const char* gA = (const char*)(cbb + (size_t)gx * 128 * DD);
        const char* gB = (const char*)(zb + (size_t)gy * 128 * DD);
#pragma unroll
        for (int i = 0; i < 16; ++i) {
            const int off = (i * 256 + t) * 16;
            const int swz = off ^ (((off >> 9) & 7) << 4);
            *(float4*)(Als + swz) = *(const float4*)(gA + off);
            *(float4*)(Bls + swz) = *(const float4*)(gB + off);
        }
        if (t < 128) ccs[t] = cc[gx * 128 + t];
    }
    __syncthreads();

    // ---- MFMA main: wave computes 64 codes x 64 rows (4x4 tiles of 16x16)
    f32x4 acc[4][4];
#pragma unroll
    for (int i = 0; i < 4; ++i)
#pragma unroll
        for (int j = 0; j < 4; ++j) acc[i][j] = (f32x4)0.0f;

    const int rA = lane & 15;
    const int kb = (lane >> 4) * 16;      // k-byte offset within 64B K-step
#pragma unroll
    for (int ks = 0; ks < 8; ++ks) {
        bf16x8 af[4], bfr[4];
#pragma unroll
        for (int i = 0; i < 4; ++i) {
            const int codeL = cw * 64 + i * 16 + rA;
            const int aaddr = codeL * 512 + ks * 64 + kb;
            af[i] = *(const bf16x8*)(Als + (aaddr ^ ((codeL & 7) << 4)));
            const int rowL = rw * 64 + i * 16 + rA;
            const int baddr = rowL * 512 + ks * 64 + kb;
            bfr[i] = *(const bf16x8*)(Bls + (baddr ^ ((rowL & 7) << 4)));
        }
#pragma unroll
        for (int i = 0; i < 4; ++i)
#pragma unroll
            for (int j = 0; j < 4; ++j)
                acc[i][j] = __builtin_amdgcn_mfma_f32_16x16x32_bf16(
                    af[i], bfr[j], acc[i][j], 0, 0, 0);
    }

    // ---- epilogue: disc, per-column (z-row) minima
    // C/D layout: col = lane&15 (z-row), row = (lane>>4)*4 + reg (code)
    float disc[4][4][4];
    float mj[4];
    const int lr = lane >> 4;
#pragma unroll
    for (int j = 0; j < 4; ++j) mj[j] = 3.0e38f;
#pragma unroll
    for (int i = 0; i < 4; ++i)
#pragma unroll
        for (int r = 0; r < 4; ++r) {
            const float ccv = ccs[cw * 64 + i * 16 + lr * 4 + r];
#pragma unroll
            for (int j = 0; j < 4; ++j) {
                const float d = fmaf(-2.0f, acc[i][j][r], ccv);
                disc[i][j][r] = d;
                mj[j] = fminf(mj[j], d);
            }
        }
#pragma unroll
    for (int j = 0; j < 4; ++j) {
        mj[j] = fminf(mj[j], __shfl_xor(mj[j], 16, 64));
        mj[j] = fminf(mj[j], __shfl_xor(mj[j], 32, 64));
        colmin_lds[cw][rw * 64 + j * 16 + (lane & 15)] = mj[j];  // replicas same
    }
    __syncthreads();

    if (t < 128) {
        const float cm = fminf(colmin_lds[0][t], colmin_lds[1][t]);
        const unsigned int enc = fenc(cm);
        const unsigned int old = atomicMin(&rowmin_u[gy * 128 + t], enc);
        const unsigned int cur = (old < enc) ? old : enc;
        thr_lds[t] = fdec(cur) + MARGIN;
    }
    __syncthreads();

#pragma unroll
    for (int j = 0; j < 4; ++j) {
        const int colL = rw * 64 + j * 16 + (lane & 15);
        const float thr = thr_lds[colL];
        const int rowg = gy * 128 + colL;
#pragma unroll
        for (int i = 0; i < 4; ++i)
#pragma unroll
            for (int r = 0; r < 4; ++r)
                if (disc[i][j][r] <= thr) {
                    const int pos = atomicAdd(&cnt[rowg], 1);
                    if (pos < CAP)
                        cand[(size_t)rowg * CAP + pos] =
                            gx * 128 + cw * 64 + i * 16 + lr * 4 + r;
                }
    }
}

// ---------------------------------------------------------------------------
// Finalize: exact fp32 rescore of each candidate with the np-faithful chain
// d2 = fl(fl(A - 2*dot_chain) + C); lexicographic argmin. One wave per row.
// ---------------------------------------------------------------------------
__global__ __launch_bounds__(256)
void vq_finalize(const float* __restrict__ z, const float* __restrict__ cb,
                 const float* __restrict__ rowA, const float* __restrict__ cc,
                 const int* __restrict__ cnt, const int* __restrict__ cand,
                 int* __restrict__ out_idx)
{
    const int t = threadIdx.x;
    const int lane = t & 63;
    const int w = t >> 6;
    const int row = blockIdx.x * 4 + w;
    int n = cnt[row];
    if (n > CAP) n = CAP;
    const float A = rowA[row];
    const float* zrow = z + (size_t)row * DD;
    float best = 3.0e38f;
    int bidx = 0x7FFFFFFF;
    for (int base = 0; base < n; base += 64) {
        const int ci = base + lane;
        float d2 = 3.0e38f;
        int code = 0x7FFFFFFF;
        if (ci < n) {
            code = cand[(size_t)row * CAP + ci];
            const float* crow = cb + (size_t)code * DD;
            float dot = 0.0f;
#pragma unroll 8
            for (int d = 0; d < DD; ++d)
                dot = fmaf(zrow[d], crow[d], dot);
            d2 = __fadd_rn(__fsub_rn(A, 2.0f * dot), cc[code]);
        }
        if (d2 < best || (d2 == best && code < bidx)) { best = d2; bidx = code; }
    }
#pragma unroll
    for (int m = 1; m < 64; m <<= 1) {
        const float ov = __shfl_xor(best, m, 64);
        const int oi = __shfl_xor(bidx, m, 64);
        if (ov < best || (ov == best && oi < bidx)) { best = ov; bidx = oi; }
    }
    if (lane == 0) out_idx[row] = bidx;
}

// ---------------------------------------------------------------------------
// Output: gather c*, z_q, loss, indices-as-float. One wave per row.
// ---------------------------------------------------------------------------
__global__ __launch_bounds__(256)
void vq_out_kernel(const float* __restrict__ z, const float* __restrict__ cb,
                   const int* __restrict__ idx, float* __restrict__ zq,
                   float* __restrict__ loss_ptr, float* __restrict__ idx_out)
{
    __shared__ float wsum[4];
    const int t = threadIdx.x;
    const int lane = t & 63;
    const int wv = t >> 6;
    const int row = blockIdx.x * 4 + wv;
    const int k = idx[row];
    const float4 z4 = *(const float4*)(z + (size_t)row * DD + lane * 4);
    const float4 c4 = *(const float4*)(cb + (size_t)k * DD + lane * 4);
    float4 d4 = make_float4(c4.x - z4.x, c4.y - z4.y, c4.z - z4.z, c4.w - z4.w);
    float ss = fmaf(d4.x, d4.x, fmaf(d4.y, d4.y, fmaf(d4.z, d4.z, d4.w * d4.w)));
#pragma unroll
    for (int m = 1; m < 64; m <<= 1) ss += __shfl_xor(ss, m, 64);
    const float mag = sqrtf(ss);
    const float scale = mag / (mag + 1e-8f);
    float4 q = make_float4(fmaf(scale, d4.x, z4.x), fmaf(scale, d4.y, z4.y),
                           fmaf(scale, d4.z, z4.z), fmaf(scale, d4.w, z4.w));
    *(float4*)(zq + (size_t)row * DD + lane * 4) = q;
    if (lane == 0) {
        wsum[wv] = ss;
        idx_out[row] = (float)k;
    }
    __syncthreads();
    if (t == 0) {
        const float s = (wsum[0] + wsum[1]) + (wsum[2] + wsum[3]);
        atomicAdd(loss_ptr, s * (1.25f / 4194304.0f));
    }
}

// ---------------------------------------------------------------------------
extern "C" void kernel_launch(void* const* d_in, const int* in_sizes, int n_in,
                              void* d_out, int out_size, void* d_ws, size_t ws_size,
                              hipStream_t stream)
{
    (void)in_sizes; (void)n_in; (void)out_size; (void)ws_size;
    const float* z = (const float*)d_in[0];
    const float* cb = (const float*)d_in[1];
    float* out = (float*)d_out;
    float* zq = out;                              // [0, 4194304)
    float* loss_ptr = out + (size_t)NROWS * DD;   // [4194304]
    float* idx_out = loss_ptr + 1;                // [4194305, +16384)

    char* ws = (char*)d_ws;
    unsigned short* zb   = (unsigned short*)(ws);                    //  8 MB
    unsigned short* cbb  = (unsigned short*)(ws + 8388608);          //  4 MB
    int*            cand = (int*)(ws + 12582912);                    //  8 MB
    int*            cnt  = (int*)(ws + 20971520);                    // 64 KB
    unsigned int*   rmin = (unsigned int*)(ws + 21037056);           // 64 KB
    float*          cc   = (float*)(ws + 21102592);                  // 32 KB
    float*          rowA = (float*)(ws + 21135360);                  // 64 KB
    int*            idxw = (int*)(ws + 21200896);                    // 64 KB

    hipMemsetAsync(cnt, 0, NROWS * sizeof(int), stream);
    hipMemsetAsync(rmin, 0xFF, NROWS * sizeof(unsigned int), stream);

    vq_convert<<<6144, 256, 0, stream>>>(z, cb, zb, cbb);
    vq_norms<<<(KC + NROWS) / 16, 256, 0, stream>>>(z, cb, cc, rowA, loss_ptr);
    vq_gemm_screen<<<dim3(KC / 128, NROWS / 128), 256, 0, stream>>>(
        cbb, zb, cc, rmin, cnt, cand);
    vq_finalize<<<NROWS / 4, 256, 0, stream>>>(z, cb, rowA, cc, cnt, cand, idxw);
    vq_out_kernel<<<NROWS / 4, 256, 0, stream>>>(z, cb, idxw, zq, loss_ptr, idx_out);
}

// Round 4
// 266.965 us; speedup vs baseline: 5.2652x; 2.6716x over previous
//
#include <hip/hip_runtime.h>
#include <math.h>

#define NROWS 16384
#define KC 8192
#define DD 256
#define CAP 128
#define MARGIN 3.0e-4f

typedef __attribute__((ext_vector_type(8))) short bf16x8;
typedef __attribute__((ext_vector_type(4))) float f32x4;

__device__ __forceinline__ unsigned short f2bf(float f) {
    unsigned int u = __float_as_uint(f);
    unsigned int r = (u + 0x7FFFu + ((u >> 16) & 1u)) >> 16;   // RNE
    return (unsigned short)r;
}
__device__ __forceinline__ unsigned int fenc(float f) {        // monotone f32->u32
    unsigned int u = __float_as_uint(f);
    return (u & 0x80000000u) ? ~u : (u | 0x80000000u);
}
__device__ __forceinline__ float fdec(unsigned int u) {
    return __uint_as_float((u & 0x80000000u) ? (u & 0x7FFFFFFFu) : ~u);
}

// np-faithful exact rescore: d2 = fl(fl(A - 2*dot_chain) + C), dot = k-ascending
// single fma chain (matches BLAS sgemm accumulation; verified rounds 2-3).
__device__ __forceinline__ float exact_d2(const float* __restrict__ zrow,
                                          const float* __restrict__ crow,
                                          float A, float C)
{
    float dot = 0.0f;
#pragma unroll 16
    for (int d = 0; d < DD; ++d) dot = fmaf(zrow[d], crow[d], dot);
    return __fadd_rn(__fsub_rn(A, 2.0f * dot), C);
}

// ---------------------------------------------------------------------------
// Prep: bf16 convert (all blocks) + np-pairwise norms (blocks < 1536) +
// cnt/rmin clears (blocks 1536..1663) + loss zero. Replaces 2 memsets + 2 kernels.
// grid = 6144 x 256.
// ---------------------------------------------------------------------------
__global__ __launch_bounds__(256)
void vq_prep(const float* __restrict__ z, const float* __restrict__ cb,
             unsigned short* __restrict__ zb, unsigned short* __restrict__ cbb,
             float* __restrict__ cc, float* __restrict__ rowA,
             int* __restrict__ cnt, unsigned int* __restrict__ rmin,
             float* __restrict__ loss_ptr)
{
    const int t = threadIdx.x;
    const int b = blockIdx.x;
    const size_t i = (size_t)b * 256 + t;            // float4 index
    {
        const float* src; unsigned short* dst; size_t off;
        if (i < 1048576) { src = z;  dst = zb;  off = i; }
        else             { src = cb; dst = cbb; off = i - 1048576; }
        float4 v = *(const float4*)(src + off * 4);
        ushort4 o;
        o.x = f2bf(v.x); o.y = f2bf(v.y); o.z = f2bf(v.z); o.w = f2bf(v.w);
        *(ushort4*)(dst + off * 4) = o;
    }
    if (b < 1536) {   // norms: 24576 units, 16 lanes each (bit-faithful np.sum(x*x))
        const int unit = b * 16 + (t >> 4);
        const int l = t & 15;
        const float* p = (unit < KC) ? (cb + (size_t)unit * DD)
                                     : (z + (size_t)(unit - KC) * DD);
        const float* q = p + 128 * (l >> 3) + (l & 7);
        float x0 = q[0];
        float r = __fmul_rn(x0, x0);
#pragma unroll
        for (int k = 1; k < 16; ++k) {
            const float x = q[8 * k];
            r = __fadd_rn(r, __fmul_rn(x, x));
        }
        r = __fadd_rn(r, __shfl_xor(r, 1, 64));
        r = __fadd_rn(r, __shfl_xor(r, 2, 64));
        r = __fadd_rn(r, __shfl_xor(r, 4, 64));
        r = __fadd_rn(r, __shfl_xor(r, 8, 64));
        if (l == 0) {
            if (unit < KC) cc[unit] = r;
            else rowA[unit - KC] = r;
        }
    } else if (b < 1664) {   // clears: 128 blocks x 256 = 32768 words
        const int u = (b - 1536) * 256 + t;
        if (u < NROWS) cnt[u] = 0;
        else rmin[u - NROWS] = 0xFFFFFFFFu;
    }
    if (i == 0) *loss_ptr = 0.0f;
}

// ---------------------------------------------------------------------------
// MFMA screen, m97-style: 128 codes x 128 rows tile, BK=64 chunks (4),
// global_load_lds staging with inverse-swizzled source (T2), swizzled ds_read.
// disc = cc - 2*dot_bf16 reuses acc; per-row tile-min -> atomicMin rowmin;
// record candidates with disc <= rowmin_so_far + MARGIN.
// grid = (row_tiles=128 fast, code_tiles=64).
// ---------------------------------------------------------------------------
__global__ __launch_bounds__(256, 2)
void vq_gemm_screen(const unsigned short* __restrict__ cbb,
                    const unsigned short* __restrict__ zb,
                    const float* __restrict__ cc,
                    unsigned int* __restrict__ rowmin_u,
                    int* __restrict__ cnt, int* __restrict__ cand)
{
    __shared__ char Als[16384];           // codes [128 rows][128 B], swizzled
    __shared__ char Bls[16384];           // z-rows [128 rows][128 B], swizzled
    __shared__ float ccs[128];
    __shared__ float colmin_lds[2][128];
    __shared__ float thr_lds[128];

    const int t = threadIdx.x;
    const int lane = t & 63;
    const int w = t >> 6;       // wave 0..3
    const int cw = w >> 1;      // code half
    const int rw = w & 1;       // row half
    const int gr = blockIdx.x;  // row tile (fast axis)
    const int gc = blockIdx.y;  // code tile

    const char* gA = (const char*)(cbb + (size_t)gc * 128 * DD);  // 512 B/row
    const char* gB = (const char*)(zb  + (size_t)gr * 128 * DD);

    if (t < 128) ccs[t] = cc[gc * 128 + t];

    f32x4 acc[4][4];
#pragma unroll
    for (int i = 0; i < 4; ++i)
#pragma unroll
        for (int j = 0; j < 4; ++j) acc[i][j] = (f32x4)0.0f;

    const int rA = lane & 15;
    const int kq = (lane >> 4) * 16;   // 16B k-slot within 64B K-step

    for (int kc = 0; kc < 4; ++kc) {
        __syncthreads();               // previous chunk's readers done
        // stage both tiles: linear LDS dest, inverse-swizzled global source
        {
            const int o0 = t * 16;
#pragma unroll
            for (int i = 0; i < 4; ++i) {
                const int o = i * 4096 + o0;
                const int row = o >> 7;
                const int col = (o & 127) ^ ((row & 7) << 4);
                const int gofs = row * 512 + kc * 128 + col;
                __builtin_amdgcn_global_load_lds(
                    (const unsigned int*)(gA + gofs),
                    (unsigned int*)(Als + i * 4096 + w * 1024), 16, 0, 0);
                __builtin_amdgcn_global_load_lds(
                    (const unsigned int*)(gB + gofs),
                    (unsigned int*)(Bls + i * 4096 + w * 1024), 16, 0, 0);
            }
        }
        __syncthreads();               // staged data visible (vmcnt drained)
#pragma unroll
        for (int ks = 0; ks < 2; ++ks) {
            bf16x8 af[4], bfr[4];
#pragma unroll
            for (int i = 0; i < 4; ++i) {
                const int c = cw * 64 + i * 16 + rA;
                af[i] = *(const bf16x8*)(Als + c * 128 +
                         ((ks * 64 + kq) ^ ((c & 7) << 4)));
                const int r = rw * 64 + i * 16 + rA;
                bfr[i] = *(const bf16x8*)(Bls + r * 128 +
                          ((ks * 64 + kq) ^ ((r & 7) << 4)));
            }
#pragma unroll
            for (int i = 0; i < 4; ++i)
#pragma unroll
                for (int j = 0; j < 4; ++j)
                    acc[i][j] = __builtin_amdgcn_mfma_f32_16x16x32_bf16(
                        af[i], bfr[j], acc[i][j], 0, 0, 0);
        }
    }

    // ---- epilogue: disc into acc, per-z-row minima
    // C/D layout: col = lane&15 (z-row), row = (lane>>4)*4 + reg (code)
    const int lr = lane >> 4;
    float mj[4];
#pragma unroll
    for (int j = 0; j < 4; ++j) mj[j] = 3.0e38f;
#pragma unroll
    for (int i = 0; i < 4; ++i) {
#pragma unroll
        for (int r = 0; r < 4; ++r) {
            const float ccv = ccs[cw * 64 + i * 16 + lr * 4 + r];
#pragma unroll
            for (int j = 0; j < 4; ++j) {
                const float d = fmaf(-2.0f, acc[i][j][r], ccv);
                acc[i][j][r] = d;
                mj[j] = fminf(mj[j], d);
            }
        }
    }
#pragma unroll
    for (int j = 0; j < 4; ++j) {
        mj[j] = fminf(mj[j], __shfl_xor(mj[j], 16, 64));
        mj[j] = fminf(mj[j], __shfl_xor(mj[j], 32, 64));
        colmin_lds[cw][rw * 64 + j * 16 + (lane & 15)] = mj[j];
    }
    __syncthreads();

    if (t < 128) {
        const float cm = fminf(colmin_lds[0][t], colmin_lds[1][t]);
        const unsigned int enc = fenc(cm);
        const unsigned int old = atomicMin(&rowmin_u[gr * 128 + t], enc);
        const unsigned int cur = (old < enc) ? old : enc;
        thr_lds[t] = fdec(cur) + MARGIN;
    }
    __syncthreads();

#pragma unroll
    for (int j = 0; j < 4; ++j) {
        const int colL = rw * 64 + j * 16 + (lane & 15);
        const float thr = thr_lds[colL];
        const int rowg = gr * 128 + colL;
#pragma unroll
        for (int i = 0; i < 4; ++i)
#pragma unroll
            for (int r = 0; r < 4; ++r)
                if (acc[i][j][r] <= thr) {
                    const int pos = atomicAdd(&cnt[rowg], 1);
                    if (pos < CAP)
                        cand[(size_t)rowg * CAP + pos] =
                            gc * 128 + cw * 64 + i * 16 + lr * 4 + r;
                }
    }
}

// ---------------------------------------------------------------------------
// Finalize + output fused. One wave per row: exact rescore of candidates
// (full-scan fallback if cnt overflowed CAP), then z_q / loss / idx writes.
// ---------------------------------------------------------------------------
__global__ __launch_bounds__(256)
void vq_finalize_out(const float* __restrict__ z, const float* __restrict__ cb,
                     const float* __restrict__ rowA, const float* __restrict__ cc,
                     const int* __restrict__ cnt, const int* __restrict__ cand,
                     float* __restrict__ zq, float* __restrict__ loss_ptr,
                     float* __restrict__ idx_out)
{
    __shared__ float wsum[4];
    const int t = threadIdx.x;
    const int lane = t & 63;
    const int w = t >> 6;
    const int row = blockIdx.x * 4 + w;
    const int n = cnt[row];
    const float A = rowA[row];
    const float* zrow = z + (size_t)row * DD;

    float best = 3.0e38f;
    int bidx = 0x7FFFFFFF;
    if (n <= CAP) {
        for (int base = 0; base < n; base += 64) {
            const int ci = base + lane;
            float d2 = 3.0e38f;
            int code = 0x7FFFFFFF;
            if (ci < n) {
                code = cand[(size_t)row * CAP + ci];
                d2 = exact_d2(zrow, cb + (size_t)code * DD, A, cc[code]);
            }
            if (d2 < best || (d2 == best && code < bidx)) { best = d2; bidx = code; }
        }
    } else {
        // overflow fallback: exact scan of all codes (correctness guarantee)
        for (int code = lane; code < KC; code += 64) {
            const float d2 = exact_d2(zrow, cb + (size_t)code * DD, A, cc[code]);
            if (d2 < best || (d2 == best && code < bidx)) { best = d2; bidx = code; }
        }
    }
#pragma unroll
    for (int m = 1; m < 64; m <<= 1) {
        const float ov = __shfl_xor(best, m, 64);
        const int oi = __shfl_xor(bidx, m, 64);
        if (ov < best || (ov == best && oi < bidx)) { best = ov; bidx = oi; }
    }

    // ---- output phase (all lanes): z_q, loss, idx
    const int k = bidx;
    const float4 z4 = *(const float4*)(zrow + lane * 4);
    const float4 c4 = *(const float4*)(cb + (size_t)k * DD + lane * 4);
    float4 d4 = make_float4(c4.x - z4.x, c4.y - z4.y, c4.z - z4.z, c4.w - z4.w);
    float ss = fmaf(d4.x, d4.x, fmaf(d4.y, d4.y, fmaf(d4.z, d4.z, d4.w * d4.w)));
#pragma unroll
    for (int m = 1; m < 64; m <<= 1) ss += __shfl_xor(ss, m, 64);
    const float mag = sqrtf(ss);
    const float scale = mag / (mag + 1e-8f);
    float4 q = make_float4(fmaf(scale, d4.x, z4.x), fmaf(scale, d4.y, z4.y),
                           fmaf(scale, d4.z, z4.z), fmaf(scale, d4.w, z4.w));
    *(float4*)(zq + (size_t)row * DD + lane * 4) = q;
    if (lane == 0) {
        wsum[w] = ss;
        idx_out[row] = (float)k;
    }
    __syncthreads();
    if (t == 0) {
        const float s = (wsum[0] + wsum[1]) + (wsum[2] + wsum[3]);
        atomicAdd(loss_ptr, s * (1.25f / 4194304.0f));
    }
}

// ---------------------------------------------------------------------------
extern "C" void kernel_launch(void* const* d_in, const int* in_sizes, int n_in,
                              void* d_out, int out_size, void* d_ws, size_t ws_size,
                              hipStream_t stream)
{
    (void)in_sizes; (void)n_in; (void)out_size; (void)ws_size;
    const float* z = (const float*)d_in[0];
    const float* cb = (const float*)d_in[1];
    float* out = (float*)d_out;
    float* zq = out;                              // [0, 4194304)
    float* loss_ptr = out + (size_t)NROWS * DD;   // [4194304]
    float* idx_out = loss_ptr + 1;                // [4194305, +16384)

    char* ws = (char*)d_ws;
    unsigned short* zb   = (unsigned short*)(ws);                  //  8 MB
    unsigned short* cbb  = (unsigned short*)(ws + 8388608);        //  4 MB
    int*            cand = (int*)(ws + 12582912);                  //  8 MB
    int*            cnt  = (int*)(ws + 20971520);                  // 64 KB
    unsigned int*   rmin = (unsigned int*)(ws + 21037056);         // 64 KB
    float*          cc   = (float*)(ws + 21102592);                // 32 KB
    float*          rowA = (float*)(ws + 21135360);                // 64 KB

    vq_prep<<<6144, 256, 0, stream>>>(z, cb, zb, cbb, cc, rowA, cnt, rmin, loss_ptr);
    vq_gemm_screen<<<dim3(NROWS / 128, KC / 128), 256, 0, stream>>>(
        cbb, zb, cc, rmin, cnt, cand);
    vq_finalize_out<<<NROWS / 4, 256, 0, stream>>>(
        z, cb, rowA, cc, cnt, cand, zq, loss_ptr, idx_out);
}